// Round 5
// baseline (589.931 us; speedup 1.0000x reference)
//
#include <hip/hip_runtime.h>
#include <math.h>

#define B_  4
#define V_  256
#define C1_ 64
#define C2_ 32
#define H0_ 128
#define H2_ 256
#define NBLK 512

typedef short bf16x8 __attribute__((ext_vector_type(8)));
typedef short bf16x4 __attribute__((ext_vector_type(4)));
typedef float f32x4  __attribute__((ext_vector_type(4)));

static __device__ __forceinline__ short f2bf(float f) {
    unsigned u = __float_as_uint(f);
    u += 0x7fffu + ((u >> 16) & 1u);          // RNE
    return (short)(u >> 16);
}

// ---------------------------------------------------------------------------
// Grid-wide barrier. Safe because all NBLK blocks are co-resident:
// __launch_bounds__(256,2) caps regs at 256/thread and LDS is ~20.5KB
// -> >=2 blocks/CU x 256 CU = 512 = NBLK. bar[0]=count, bar[1]=generation,
// zeroed by hipMemsetAsync before launch.
// ---------------------------------------------------------------------------
static __device__ __forceinline__ void gbar(int* bar) {
    __syncthreads();
    if (threadIdx.x == 0) {
        __threadfence();                              // release own writes (agent scope)
        int g = __hip_atomic_load(bar + 1, __ATOMIC_RELAXED, __HIP_MEMORY_SCOPE_AGENT);
        int v = __hip_atomic_fetch_add(bar, 1, __ATOMIC_ACQ_REL, __HIP_MEMORY_SCOPE_AGENT);
        if (v == NBLK - 1) {
            __hip_atomic_store(bar, 0, __ATOMIC_RELAXED, __HIP_MEMORY_SCOPE_AGENT);
            __hip_atomic_store(bar + 1, g + 1, __ATOMIC_RELEASE, __HIP_MEMORY_SCOPE_AGENT);
        } else {
            while (__hip_atomic_load(bar + 1, __ATOMIC_RELAXED, __HIP_MEMORY_SCOPE_AGENT) == g)
                __builtin_amdgcn_s_sleep(2);
        }
        __threadfence();                              // acquire others' writes
    }
    __syncthreads();
}

// ---------------------------------------------------------------------------
// Weight transpose+bf16 (blocks 0..159 run this in phase 0).
// wsW (shorts): W1cT1[128*32] | W2T1[128*128] | W1cT2[128*32] | W2T2[128*128]
// ---------------------------------------------------------------------------
static __device__ void prep_dev(int idx,
    const float* __restrict__ W1c1, const float* __restrict__ W21,
    const float* __restrict__ W1c2, const float* __restrict__ W22,
    short* __restrict__ wsW)
{
    if (idx < 4096) {
        int n = idx >> 5, k = idx & 31;
        wsW[idx] = f2bf(W1c1[k * H0_ + n]);
    } else if (idx < 20480) {
        int t = idx - 4096; int n = t >> 7, k = t & 127;
        wsW[idx] = f2bf(W21[k * H0_ + n]);
    } else if (idx < 24576) {
        int t = idx - 20480; int n = t >> 5, k = t & 31;
        wsW[idx] = f2bf(W1c2[k * H0_ + n]);
    } else if (idx < 40960) {
        int t = idx - 24576; int n = t >> 7, k = t & 127;
        wsW[idx] = f2bf(W22[k * H0_ + n]);
    }
}

// ---------------------------------------------------------------------------
// Per-node hoist for 2 nodes: P = x@(W1a-W1b)+b1, Q = x@W1b.
// Waves 0-1 compute P, waves 2-3 compute Q (wave-uniform split).
// ---------------------------------------------------------------------------
template <int CIN>
static __device__ void pre2nodes(int g,
    const float* __restrict__ x, const float* __restrict__ W1,
    const float* __restrict__ b1, float* __restrict__ P, float* __restrict__ Q,
    float* s_x /* >= 2*CIN floats */)
{
    const int tid = threadIdx.x;
    const int n   = tid & 127;
    const bool isP = tid < 128;
    for (int idx = tid; idx < 2 * CIN; idx += 256) s_x[idx] = x[g * 2 * CIN + idx];
    __syncthreads();

    float a0 = isP ? b1[n] : 0.f, a1 = a0;
    #pragma unroll 2
    for (int k = 0; k < CIN; k += 4) {
        float4 wv;
        if (isP) {
            wv.x = W1[(k + 0) * H0_ + n] - W1[(CIN + k + 0) * H0_ + n];
            wv.y = W1[(k + 1) * H0_ + n] - W1[(CIN + k + 1) * H0_ + n];
            wv.z = W1[(k + 2) * H0_ + n] - W1[(CIN + k + 2) * H0_ + n];
            wv.w = W1[(k + 3) * H0_ + n] - W1[(CIN + k + 3) * H0_ + n];
        } else {
            wv.x = W1[(CIN + k + 0) * H0_ + n];
            wv.y = W1[(CIN + k + 1) * H0_ + n];
            wv.z = W1[(CIN + k + 2) * H0_ + n];
            wv.w = W1[(CIN + k + 3) * H0_ + n];
        }
        float4 x0 = *reinterpret_cast<const float4*>(&s_x[k]);
        float4 x1v = *reinterpret_cast<const float4*>(&s_x[CIN + k]);
        a0 = fmaf(x0.x, wv.x, a0);  a1 = fmaf(x1v.x, wv.x, a1);
        a0 = fmaf(x0.y, wv.y, a0);  a1 = fmaf(x1v.y, wv.y, a1);
        a0 = fmaf(x0.z, wv.z, a0);  a1 = fmaf(x1v.z, wv.z, a1);
        a0 = fmaf(x0.w, wv.w, a0);  a1 = fmaf(x1v.w, wv.w, a1);
    }
    float* dst = isP ? P : Q;
    dst[(g * 2 + 0) * H0_ + n] = a0;
    dst[(g * 2 + 1) * H0_ + n] = a1;
}

// ---------------------------------------------------------------------------
// Dense EdgeConvE: 2 nodes per block, ALL 256 j's computed (no compaction,
// no gathers -- everything coalesced); adjacency masking in epilogue 2.
// Wave w handles 16-edge tiles w, w+4, w+8, w+12 per node.
// GEMM1 (M=neur, N=edges): A=W1cT frags, B=e-frag, C-init=P[i]+Q[j].
// GEMM2 (M=edges, N=neur): B2=W2T persistent in regs; h1 via wave-private LDS.
// ---------------------------------------------------------------------------
static __device__ void conv_dense(int g,
    const int* __restrict__ adj, const float* __restrict__ e,
    const float* __restrict__ P, const float* __restrict__ Q,
    const short* __restrict__ W1cT, const short* __restrict__ W2T,
    const float* __restrict__ b2, float* __restrict__ out,
    short (*s_h1)[136], float (*s_m)[H0_])
{
    const int tid  = threadIdx.x;
    const int w    = tid >> 6;
    const int lane = tid & 63;
    const int l15  = lane & 15;
    const int quad = lane >> 4;

    bf16x8 B2[8][4];
    #pragma unroll
    for (int nt = 0; nt < 8; ++nt)
        #pragma unroll
        for (int kk = 0; kk < 4; ++kk)
            B2[nt][kk] = *(const bf16x8*)(W2T + (nt * 16 + l15) * H0_ + kk * 32 + quad * 8);

    for (int nd = 0; nd < 2; ++nd) {
        const int bi = g * 2 + nd;
        const int b  = bi >> 8;

        f32x4 Pp[8];
        #pragma unroll
        for (int nt = 0; nt < 8; ++nt)
            Pp[nt] = *(const f32x4*)(P + bi * H0_ + nt * 16 + quad * 4);

        float vmax[8];
        #pragma unroll
        for (int nt = 0; nt < 8; ++nt) vmax[nt] = -1e30f;

        for (int tile = w; tile < 16; tile += 4) {
            const int j0 = tile * 16;
            const int jr = j0 + l15;                 // this lane's edge col

            // e-fragment (coalesced 16 consecutive rows)
            const float* er = e + (bi * V_ + jr) * C2_ + quad * 8;
            float4 e0 = *(const float4*)(er);
            float4 e1 = *(const float4*)(er + 4);
            bf16x8 Bf;
            Bf[0] = f2bf(e0.x); Bf[1] = f2bf(e0.y); Bf[2] = f2bf(e0.z); Bf[3] = f2bf(e0.w);
            Bf[4] = f2bf(e1.x); Bf[5] = f2bf(e1.y); Bf[6] = f2bf(e1.z); Bf[7] = f2bf(e1.w);

            const float* Qr = Q + (b * V_ + jr) * H0_;
            const int4 av = *(const int4*)(adj + bi * V_ + j0 + quad * 4);

            // GEMM1 + epilogue1 (relu, bf16 -> wave-private LDS rows)
            #pragma unroll
            for (int nt = 0; nt < 8; ++nt) {
                bf16x8 A1 = *(const bf16x8*)(W1cT + (nt * 16 + l15) * C2_ + quad * 8);
                f32x4 c4 = Pp[nt] + *(const f32x4*)(Qr + nt * 16 + quad * 4);
                f32x4 acc = __builtin_amdgcn_mfma_f32_16x16x32_bf16(A1, Bf, c4, 0, 0, 0);
                bf16x4 hv;
                hv[0] = f2bf(fmaxf(acc[0], 0.f));
                hv[1] = f2bf(fmaxf(acc[1], 0.f));
                hv[2] = f2bf(fmaxf(acc[2], 0.f));
                hv[3] = f2bf(fmaxf(acc[3], 0.f));
                *(bf16x4*)(&s_h1[w * 16 + l15][nt * 16 + quad * 4]) = hv;
            }

            // GEMM2 (wave-private rows; B2 in regs)
            f32x4 acc2[8];
            #pragma unroll
            for (int nt = 0; nt < 8; ++nt) { f32x4 z = {0.f,0.f,0.f,0.f}; acc2[nt] = z; }
            #pragma unroll
            for (int kk = 0; kk < 4; ++kk) {
                bf16x8 A2 = *(const bf16x8*)(&s_h1[w * 16 + l15][kk * 32 + quad * 8]);
                #pragma unroll
                for (int nt = 0; nt < 8; ++nt)
                    acc2[nt] = __builtin_amdgcn_mfma_f32_16x16x32_bf16(A2, B2[nt][kk], acc2[nt], 0, 0, 0);
            }
            // epilogue2: adjacency-masked max (rows = edges j0+quad*4+r)
            #pragma unroll
            for (int nt = 0; nt < 8; ++nt) {
                float m0 = av.x > 0 ? acc2[nt][0] : -1e30f;
                float m1 = av.y > 0 ? acc2[nt][1] : -1e30f;
                float m2 = av.z > 0 ? acc2[nt][2] : -1e30f;
                float m3 = av.w > 0 ? acc2[nt][3] : -1e30f;
                vmax[nt] = fmaxf(vmax[nt], fmaxf(fmaxf(m0, m1), fmaxf(m2, m3)));
            }
        }

        // reduce across quads, then waves; bias+relu at the end.
        #pragma unroll
        for (int nt = 0; nt < 8; ++nt) {
            float p = vmax[nt];
            p = fmaxf(p, __shfl_xor(p, 16, 64));
            p = fmaxf(p, __shfl_xor(p, 32, 64));
            if (quad == 0) s_m[w][nt * 16 + l15] = p;
        }
        __syncthreads();
        if (tid < H0_) {
            float m = fmaxf(fmaxf(s_m[0][tid], s_m[1][tid]),
                            fmaxf(s_m[2][tid], s_m[3][tid]));
            out[bi * H0_ + tid] = fmaxf(m + b2[tid], 0.f);   // isolated -> 0
        }
        __syncthreads();
    }
}

// ---------------------------------------------------------------------------
// Pair hoist for 2 nodes: Ai = x2@W3[H0:]+b3, Aj = x2@W3[:H0].
// ---------------------------------------------------------------------------
static __device__ void pair_pre2(int g,
    const float* __restrict__ x2, const float* __restrict__ W3,
    const float* __restrict__ b3, float* __restrict__ Ai, float* __restrict__ Aj,
    float* s_x /* >= 256 floats */)
{
    const int n = threadIdx.x;
    s_x[n] = x2[g * 2 * H0_ + n];                      // 2 nodes x 128
    __syncthreads();

    float aI0 = b3[n], aI1 = aI0, aJ0 = 0.f, aJ1 = 0.f;
    #pragma unroll 2
    for (int k = 0; k < H0_; k += 4) {
        float4 wj, wi;
        wj.x = W3[(k + 0) * H2_ + n];  wi.x = W3[(H0_ + k + 0) * H2_ + n];
        wj.y = W3[(k + 1) * H2_ + n];  wi.y = W3[(H0_ + k + 1) * H2_ + n];
        wj.z = W3[(k + 2) * H2_ + n];  wi.z = W3[(H0_ + k + 2) * H2_ + n];
        wj.w = W3[(k + 3) * H2_ + n];  wi.w = W3[(H0_ + k + 3) * H2_ + n];
        float4 x0 = *reinterpret_cast<const float4*>(&s_x[k]);
        float4 x1v = *reinterpret_cast<const float4*>(&s_x[H0_ + k]);
        aJ0 = fmaf(x0.x, wj.x, aJ0);  aI0 = fmaf(x0.x, wi.x, aI0);
        aJ0 = fmaf(x0.y, wj.y, aJ0);  aI0 = fmaf(x0.y, wi.y, aI0);
        aJ0 = fmaf(x0.z, wj.z, aJ0);  aI0 = fmaf(x0.z, wi.z, aI0);
        aJ0 = fmaf(x0.w, wj.w, aJ0);  aI0 = fmaf(x0.w, wi.w, aI0);
        aJ1 = fmaf(x1v.x, wj.x, aJ1); aI1 = fmaf(x1v.x, wi.x, aI1);
        aJ1 = fmaf(x1v.y, wj.y, aJ1); aI1 = fmaf(x1v.y, wi.y, aI1);
        aJ1 = fmaf(x1v.z, wj.z, aJ1); aI1 = fmaf(x1v.z, wi.z, aI1);
        aJ1 = fmaf(x1v.w, wj.w, aJ1); aI1 = fmaf(x1v.w, wi.w, aI1);
    }
    Ai[(g * 2 + 0) * H2_ + n] = aI0;
    Ai[(g * 2 + 1) * H2_ + n] = aI1;
    Aj[(g * 2 + 0) * H2_ + n] = aJ0;
    Aj[(g * 2 + 1) * H2_ + n] = aJ1;
}

// ---------------------------------------------------------------------------
// Pair output: 2 i's per block; waves 0-1 -> i0, waves 2-3 -> i1, each wave
// covers 128 j's, 4 per step; lane=(jj,c) = 4 j x 16-float channel chunk.
// ---------------------------------------------------------------------------
static __device__ void pair_out2(int g,
    const float* __restrict__ Ai, const float* __restrict__ Aj,
    const float* __restrict__ Wo, const float* __restrict__ bo,
    float* __restrict__ out)
{
    const int w    = threadIdx.x >> 6;
    const int lane = threadIdx.x & 63;
    const int bi   = g * 2 + (w >> 1);
    const int b    = bi >> 8;
    const int jj   = lane >> 4;
    const int c    = lane & 15;

    const float* ai = Ai + bi * H2_ + c * 16;
    float4 a0 = *(const float4*)(ai);
    float4 a1 = *(const float4*)(ai + 4);
    float4 a2 = *(const float4*)(ai + 8);
    float4 a3 = *(const float4*)(ai + 12);
    const float* wo = Wo + c * 16;
    float4 w0 = *(const float4*)(wo);
    float4 w1 = *(const float4*)(wo + 4);
    float4 w2 = *(const float4*)(wo + 8);
    float4 w3 = *(const float4*)(wo + 12);
    const float bo0 = bo[0];

    const int jbase = (w & 1) * 128;
    for (int j0 = jbase; j0 < jbase + 128; j0 += 4) {
        const int j = j0 + jj;
        const float* aj = Aj + (b * V_ + j) * H2_ + c * 16;
        float4 q0 = *(const float4*)(aj);
        float4 q1 = *(const float4*)(aj + 4);
        float4 q2 = *(const float4*)(aj + 8);
        float4 q3 = *(const float4*)(aj + 12);
        float p;
        p = fmaxf(a0.x + q0.x, 0.f) * w0.x;
        p = fmaf(fmaxf(a0.y + q0.y, 0.f), w0.y, p);
        p = fmaf(fmaxf(a0.z + q0.z, 0.f), w0.z, p);
        p = fmaf(fmaxf(a0.w + q0.w, 0.f), w0.w, p);
        p = fmaf(fmaxf(a1.x + q1.x, 0.f), w1.x, p);
        p = fmaf(fmaxf(a1.y + q1.y, 0.f), w1.y, p);
        p = fmaf(fmaxf(a1.z + q1.z, 0.f), w1.z, p);
        p = fmaf(fmaxf(a1.w + q1.w, 0.f), w1.w, p);
        p = fmaf(fmaxf(a2.x + q2.x, 0.f), w2.x, p);
        p = fmaf(fmaxf(a2.y + q2.y, 0.f), w2.y, p);
        p = fmaf(fmaxf(a2.z + q2.z, 0.f), w2.z, p);
        p = fmaf(fmaxf(a2.w + q2.w, 0.f), w2.w, p);
        p = fmaf(fmaxf(a3.x + q3.x, 0.f), w3.x, p);
        p = fmaf(fmaxf(a3.y + q3.y, 0.f), w3.y, p);
        p = fmaf(fmaxf(a3.z + q3.z, 0.f), w3.z, p);
        p = fmaf(fmaxf(a3.w + q3.w, 0.f), w3.w, p);
        #pragma unroll
        for (int off = 1; off < 16; off <<= 1)
            p += __shfl_xor(p, off, 64);
        if (c == 0)
            out[bi * V_ + j] = 1.f / (1.f + __builtin_expf(-(p + bo0)));
    }
}

// ---------------------------------------------------------------------------
// The whole network in one persistent kernel, phases separated by grid
// barriers (all 512 blocks co-resident; see gbar()).
// ---------------------------------------------------------------------------
__global__ __launch_bounds__(256, 2) void fused_k(
    const int* __restrict__ adj, const float* __restrict__ xf,
    const float* __restrict__ ea,
    const float* __restrict__ ec1W1, const float* __restrict__ ec1b1,
    const float* __restrict__ ec1W2, const float* __restrict__ ec1b2,
    const float* __restrict__ ec2W1, const float* __restrict__ ec2b1,
    const float* __restrict__ ec2W2, const float* __restrict__ ec2b2,
    const float* __restrict__ h3W, const float* __restrict__ h3b,
    const float* __restrict__ oW, const float* __restrict__ ob,
    float* __restrict__ out, int* bar,
    float* x1, float* x2, float* P, float* Q, float* Ai, float* Aj, short* wsW)
{
    __shared__ __align__(16) short s_h1[64][136];
    __shared__ __align__(16) float s_m[4][H0_];
    __shared__ __align__(16) float s_x[2 * H0_];

    const int g = blockIdx.x;

    // phase 0: conv1 P/Q hoist + weight prep
    pre2nodes<C1_>(g, xf, ec1W1, ec1b1, P, Q, s_x);
    if (g < 160)
        prep_dev(g * 256 + threadIdx.x, ec1W1 + 2 * C1_ * H0_, ec1W2,
                 ec2W1 + 2 * H0_ * H0_, ec2W2, wsW);
    gbar(bar);
    // phase 1: conv1 dense
    conv_dense(g, adj, ea, P, Q, wsW, wsW + 4096, ec1b2, x1, s_h1, s_m);
    gbar(bar);
    // phase 2: conv2 P/Q hoist
    pre2nodes<H0_>(g, x1, ec2W1, ec2b1, P, Q, s_x);
    gbar(bar);
    // phase 3: conv2 dense
    conv_dense(g, adj, ea, P, Q, wsW + 20480, wsW + 24576, ec2b2, x2, s_h1, s_m);
    gbar(bar);
    // phase 4: pair hoist
    pair_pre2(g, x2, h3W, h3b, Ai, Aj, s_x);
    gbar(bar);
    // phase 5: pair output
    pair_out2(g, Ai, Aj, oW, ob, out);
}

// ---------------------------------------------------------------------------
extern "C" void kernel_launch(void* const* d_in, const int* in_sizes, int n_in,
                              void* d_out, int out_size, void* d_ws, size_t ws_size,
                              hipStream_t stream) {
    const int*   adj   = (const int*)  d_in[0];
    const float* xf    = (const float*)d_in[1];
    const float* ea    = (const float*)d_in[2];
    const float* ec1W1 = (const float*)d_in[3];
    const float* ec1b1 = (const float*)d_in[4];
    const float* ec1W2 = (const float*)d_in[5];
    const float* ec1b2 = (const float*)d_in[6];
    const float* ec2W1 = (const float*)d_in[7];
    const float* ec2b1 = (const float*)d_in[8];
    const float* ec2W2 = (const float*)d_in[9];
    const float* ec2b2 = (const float*)d_in[10];
    const float* h3W   = (const float*)d_in[11];
    const float* h3b   = (const float*)d_in[12];
    const float* oW    = (const float*)d_in[13];
    const float* ob    = (const float*)d_in[14];
    float* out = (float*)d_out;

    const int NV = B_ * V_;
    int*   bar = (int*)d_ws;                       // 2 ints, zeroed below
    float* base = (float*)((char*)d_ws + 256);
    float* x1 = base;                              // NV*H0
    float* x2 = x1 + NV * H0_;                     // NV*H0
    float* P  = x2 + NV * H0_;                     // NV*H0
    float* Q  = P  + NV * H0_;                     // NV*H0
    float* Ai = Q  + NV * H0_;                     // NV*H2
    float* Aj = Ai + NV * H2_;                     // NV*H2
    short* wsW = (short*)(Aj + NV * H2_);          // 40960 bf16

    hipMemsetAsync(bar, 0, 2 * sizeof(int), stream);
    fused_k<<<NBLK, 256, 0, stream>>>(adj, xf, ea,
        ec1W1, ec1b1, ec1W2, ec1b2, ec2W1, ec2b1, ec2W2, ec2b2,
        h3W, h3b, oW, ob, out, bar, x1, x2, P, Q, Ai, Aj, wsW);
}

// Round 6
// 270.795 us; speedup vs baseline: 2.1785x; 2.1785x over previous
//
#include <hip/hip_runtime.h>
#include <math.h>

#define B_  4
#define V_  256
#define C1_ 64
#define C2_ 32
#define H0_ 128
#define H2_ 256

typedef short bf16x8 __attribute__((ext_vector_type(8)));
typedef short bf16x4 __attribute__((ext_vector_type(4)));
typedef float f32x4  __attribute__((ext_vector_type(4)));

static __device__ __forceinline__ short f2bf(float f) {
    unsigned u = __float_as_uint(f);
    u += 0x7fffu + ((u >> 16) & 1u);          // RNE
    return (short)(u >> 16);
}

// ---------------------------------------------------------------------------
// Prep (K1, blocks >= 256): bf16+transpose MFMA weight fragments, and fp32
// transposed copies for the per-node tails.
//  wsW (shorts): W1cT1[4096] | W2T1[16384] | W1cT2[4096] | W2T2[16384]
//  WPT[n][k] = W1a2[k][n]-W1b2[k][n]   (128x128)
//  WQT[n][k] = W1b2[k][n]              (128x128)
//  WJT[n][k] = W3[k][n]                (256x128)
//  WIT[n][k] = W3[128+k][n]            (256x128)
// ---------------------------------------------------------------------------
static __device__ void prep_dev(int idx,
    const float* __restrict__ W1c1, const float* __restrict__ W21,
    const float* __restrict__ W1c2, const float* __restrict__ W22,
    const float* __restrict__ Wc2,  const float* __restrict__ W3,
    short* __restrict__ wsW, float* __restrict__ WPT, float* __restrict__ WQT,
    float* __restrict__ WJT, float* __restrict__ WIT)
{
    if (idx < 4096) {
        int n = idx >> 5, k = idx & 31;
        wsW[idx] = f2bf(W1c1[k * H0_ + n]);
    } else if (idx < 20480) {
        int t = idx - 4096; int n = t >> 7, k = t & 127;
        wsW[idx] = f2bf(W21[k * H0_ + n]);
    } else if (idx < 24576) {
        int t = idx - 20480; int n = t >> 5, k = t & 31;
        wsW[idx] = f2bf(W1c2[k * H0_ + n]);
    } else if (idx < 40960) {
        int t = idx - 24576; int n = t >> 7, k = t & 127;
        wsW[idx] = f2bf(W22[k * H0_ + n]);
    } else if (idx < 57344) {
        int t = idx - 40960; int n = t >> 7, k = t & 127;
        WPT[t] = Wc2[k * H0_ + n] - Wc2[(H0_ + k) * H0_ + n];
    } else if (idx < 73728) {
        int t = idx - 57344; int n = t >> 7, k = t & 127;
        WQT[t] = Wc2[(H0_ + k) * H0_ + n];
    } else if (idx < 106496) {
        int t = idx - 73728; int n = t >> 7, k = t & 127;
        WJT[t] = W3[k * H2_ + n];
    } else if (idx < 139264) {
        int t = idx - 106496; int n = t >> 7, k = t & 127;
        WIT[t] = W3[(H0_ + k) * H2_ + n];
    }
}

// ---------------------------------------------------------------------------
// Conv1 hoist, 4 nodes/block (K1 blocks < 256): P1 = x@(W1a-W1b)+b1, Q1=x@W1b.
// ---------------------------------------------------------------------------
template <int CIN>
static __device__ void node_pre4(int g,
    const float* __restrict__ x, const float* __restrict__ W1,
    const float* __restrict__ b1, float* __restrict__ P, float* __restrict__ Q)
{
    const int bi0 = g * 4;
    const int tid = threadIdx.x;
    const int n   = tid & 127;
    const bool isP = tid < 128;             // wave-uniform split

    __shared__ __align__(16) float s_x4[4][CIN];
    for (int idx = tid; idx < 4 * CIN; idx += 256)
        s_x4[idx / CIN][idx % CIN] = x[bi0 * CIN + idx];
    __syncthreads();

    float acc[4];
    float binit = isP ? b1[n] : 0.f;
    #pragma unroll
    for (int nd = 0; nd < 4; ++nd) acc[nd] = binit;

    for (int k = 0; k < CIN; k += 4) {
        float4 wv;
        if (isP) {
            wv.x = W1[(k + 0) * H0_ + n] - W1[(CIN + k + 0) * H0_ + n];
            wv.y = W1[(k + 1) * H0_ + n] - W1[(CIN + k + 1) * H0_ + n];
            wv.z = W1[(k + 2) * H0_ + n] - W1[(CIN + k + 2) * H0_ + n];
            wv.w = W1[(k + 3) * H0_ + n] - W1[(CIN + k + 3) * H0_ + n];
        } else {
            wv.x = W1[(CIN + k + 0) * H0_ + n];
            wv.y = W1[(CIN + k + 1) * H0_ + n];
            wv.z = W1[(CIN + k + 2) * H0_ + n];
            wv.w = W1[(CIN + k + 3) * H0_ + n];
        }
        #pragma unroll
        for (int nd = 0; nd < 4; ++nd) {
            float4 xv = *reinterpret_cast<const float4*>(&s_x4[nd][k]);
            acc[nd] = fmaf(xv.x, wv.x, acc[nd]);
            acc[nd] = fmaf(xv.y, wv.y, acc[nd]);
            acc[nd] = fmaf(xv.z, wv.z, acc[nd]);
            acc[nd] = fmaf(xv.w, wv.w, acc[nd]);
        }
    }
    float* dst = isP ? P : Q;
    #pragma unroll
    for (int nd = 0; nd < 4; ++nd)
        dst[(bi0 + nd) * H0_ + n] = acc[nd];
}

__global__ __launch_bounds__(256) void pre1_k(
    const float* __restrict__ xf, const float* __restrict__ ec1W1,
    const float* __restrict__ ec1b1, float* __restrict__ P1, float* __restrict__ Q1,
    const float* __restrict__ W1c1, const float* __restrict__ W21,
    const float* __restrict__ W1c2, const float* __restrict__ W22,
    const float* __restrict__ Wc2,  const float* __restrict__ W3,
    short* __restrict__ wsW, float* __restrict__ WPT, float* __restrict__ WQT,
    float* __restrict__ WJT, float* __restrict__ WIT)
{
    if (blockIdx.x < 256)
        node_pre4<C1_>(blockIdx.x, xf, ec1W1, ec1b1, P1, Q1);
    else
        prep_dev((blockIdx.x - 256) * 256 + threadIdx.x,
                 W1c1, W21, W1c2, W22, Wc2, W3, wsW, WPT, WQT, WJT, WIT);
}

// ---------------------------------------------------------------------------
// Dense EdgeConvE for ONE node; result (post max+bias+relu) left in s_x[128].
// 4 waves. Per 64-edge chunk:
//   GEMM1: wave w stages edges [w*16,w*16+16): 8 MFMA (M=neurons,N=edges),
//          C-init = P[i]+Q[j]; relu->bf16 -> s_h1 rows.  __syncthreads.
//   GEMM2: wave w computes N-tiles {2w,2w+1} over all 64 rows:
//          B2 = 32 VGPRs persistent; 16 ds_read_b128 reused x2.
//   Mask+max per 16-row tile with adjacency int4.  __syncthreads.
// ---------------------------------------------------------------------------
static __device__ void conv_node(int bi,
    const int* __restrict__ adj, const float* __restrict__ e,
    const float* __restrict__ P, const float* __restrict__ Q,
    const short* __restrict__ W1cT, const short* __restrict__ W2T,
    const float* __restrict__ b2,
    short (*s_h1)[136], float* s_x)
{
    const int b    = bi >> 8;
    const int tid  = threadIdx.x;
    const int w    = tid >> 6;
    const int lane = tid & 63;
    const int l15  = lane & 15;
    const int quad = lane >> 4;

    // persistent: GEMM2 B-fragments for this wave's 2 N-tiles (32 VGPRs)
    bf16x8 B2[2][4];
    #pragma unroll
    for (int t = 0; t < 2; ++t)
        #pragma unroll
        for (int kk = 0; kk < 4; ++kk)
            B2[t][kk] = *(const bf16x8*)(W2T + ((2 * w + t) * 16 + l15) * H0_ + kk * 32 + quad * 8);

    // P fragments (neuron rows) for GEMM1 C-init
    f32x4 Pp[8];
    #pragma unroll
    for (int nt = 0; nt < 8; ++nt)
        Pp[nt] = *(const f32x4*)(P + bi * H0_ + nt * 16 + quad * 4);

    float vmax[2] = {-1e30f, -1e30f};

    for (int c = 0; c < 4; ++c) {
        // ---- GEMM1: stage h1 for this wave's 16 edges ----
        const int jr = c * 64 + w * 16 + l15;
        const float* er = e + (bi * V_ + jr) * C2_ + quad * 8;
        float4 e0 = *(const float4*)(er);
        float4 e1 = *(const float4*)(er + 4);
        bf16x8 Bf;
        Bf[0] = f2bf(e0.x); Bf[1] = f2bf(e0.y); Bf[2] = f2bf(e0.z); Bf[3] = f2bf(e0.w);
        Bf[4] = f2bf(e1.x); Bf[5] = f2bf(e1.y); Bf[6] = f2bf(e1.z); Bf[7] = f2bf(e1.w);
        const float* Qr = Q + (b * V_ + jr) * H0_;
        #pragma unroll
        for (int nt = 0; nt < 8; ++nt) {
            bf16x8 A1 = *(const bf16x8*)(W1cT + (nt * 16 + l15) * C2_ + quad * 8);
            f32x4 c4 = Pp[nt] + *(const f32x4*)(Qr + nt * 16 + quad * 4);
            f32x4 a = __builtin_amdgcn_mfma_f32_16x16x32_bf16(A1, Bf, c4, 0, 0, 0);
            bf16x4 hv;
            hv[0] = f2bf(fmaxf(a[0], 0.f));
            hv[1] = f2bf(fmaxf(a[1], 0.f));
            hv[2] = f2bf(fmaxf(a[2], 0.f));
            hv[3] = f2bf(fmaxf(a[3], 0.f));
            *(bf16x4*)(&s_h1[w * 16 + l15][nt * 16 + quad * 4]) = hv;
        }
        __syncthreads();

        // ---- GEMM2: this wave's 2 N-tiles over all 64 staged rows ----
        #pragma unroll
        for (int m = 0; m < 4; ++m) {
            f32x4 acc0 = {0.f, 0.f, 0.f, 0.f}, acc1 = {0.f, 0.f, 0.f, 0.f};
            #pragma unroll
            for (int kk = 0; kk < 4; ++kk) {
                bf16x8 A2 = *(const bf16x8*)(&s_h1[m * 16 + l15][kk * 32 + quad * 8]);
                acc0 = __builtin_amdgcn_mfma_f32_16x16x32_bf16(A2, B2[0][kk], acc0, 0, 0, 0);
                acc1 = __builtin_amdgcn_mfma_f32_16x16x32_bf16(A2, B2[1][kk], acc1, 0, 0, 0);
            }
            // rows of this tile: j = c*64 + m*16 + quad*4 + r
            const int4 av = *(const int4*)(adj + bi * V_ + c * 64 + m * 16 + quad * 4);
            float m00 = av.x > 0 ? acc0[0] : -1e30f;
            float m01 = av.y > 0 ? acc0[1] : -1e30f;
            float m02 = av.z > 0 ? acc0[2] : -1e30f;
            float m03 = av.w > 0 ? acc0[3] : -1e30f;
            vmax[0] = fmaxf(vmax[0], fmaxf(fmaxf(m00, m01), fmaxf(m02, m03)));
            float m10 = av.x > 0 ? acc1[0] : -1e30f;
            float m11 = av.y > 0 ? acc1[1] : -1e30f;
            float m12 = av.z > 0 ? acc1[2] : -1e30f;
            float m13 = av.w > 0 ? acc1[3] : -1e30f;
            vmax[1] = fmaxf(vmax[1], fmaxf(fmaxf(m10, m11), fmaxf(m12, m13)));
        }
        __syncthreads();                     // protect s_h1 for next chunk
    }

    // cross-quad max; bias+relu; write node output row to s_x
    #pragma unroll
    for (int t = 0; t < 2; ++t) {
        float p = vmax[t];
        p = fmaxf(p, __shfl_xor(p, 16, 64));
        p = fmaxf(p, __shfl_xor(p, 32, 64));
        if (quad == 0) {
            const int n = (2 * w + t) * 16 + l15;
            s_x[n] = fmaxf(p + b2[n], 0.f);  // isolated node -> 0
        }
    }
    __syncthreads();
}

// ---------------------------------------------------------------------------
// Conv1 + fused conv2-hoist tail: P2 = x1@(W1a2-W1b2)+b1_2, Q2 = x1@W1b2
// (depends only on this node's own x1 row -> no cross-block dependency).
// Split-k across thread halves using transposed fp32 weights.
// ---------------------------------------------------------------------------
__global__ __launch_bounds__(256, 2) void conv1_k(
    const int* __restrict__ adj, const float* __restrict__ e,
    const float* __restrict__ P1, const float* __restrict__ Q1,
    const short* __restrict__ W1cT, const short* __restrict__ W2T,
    const float* __restrict__ b2,
    const float* __restrict__ WPT, const float* __restrict__ WQT,
    const float* __restrict__ b1_2,
    float* __restrict__ P2, float* __restrict__ Q2)
{
    __shared__ __align__(16) short s_h1[64][136];
    __shared__ __align__(16) float s_x[H0_];
    __shared__ float s_pp[2][H0_], s_qq[2][H0_];

    const int bi = blockIdx.x;
    conv_node(bi, adj, e, P1, Q1, W1cT, W2T, b2, s_h1, s_x);

    const int tid = threadIdx.x, n = tid & 127, half = tid >> 7;
    float xP = 0.f, xQ = 0.f;
    const float* wp = WPT + n * H0_ + half * 64;
    const float* wq = WQT + n * H0_ + half * 64;
    const float* xs = s_x + half * 64;
    #pragma unroll 4
    for (int k = 0; k < 64; k += 4) {
        float4 x = *(const float4*)(xs + k);
        float4 a = *(const float4*)(wp + k);
        float4 q = *(const float4*)(wq + k);
        xP = fmaf(x.x, a.x, xP);  xQ = fmaf(x.x, q.x, xQ);
        xP = fmaf(x.y, a.y, xP);  xQ = fmaf(x.y, q.y, xQ);
        xP = fmaf(x.z, a.z, xP);  xQ = fmaf(x.z, q.z, xQ);
        xP = fmaf(x.w, a.w, xP);  xQ = fmaf(x.w, q.w, xQ);
    }
    s_pp[half][n] = xP;
    s_qq[half][n] = xQ;
    __syncthreads();
    if (half == 0) P2[bi * H0_ + n] = s_pp[0][n] + s_pp[1][n] + b1_2[n];
    else           Q2[bi * H0_ + n] = s_qq[0][n] + s_qq[1][n];
}

// ---------------------------------------------------------------------------
// Conv2 + fused pair-hoist tail: Ai = x2@W3[H0:]+b3, Aj = x2@W3[:H0]
// (per-node only). Thread = one of 256 H2 neurons; transposed fp32 weights.
// ---------------------------------------------------------------------------
__global__ __launch_bounds__(256, 2) void conv2_k(
    const int* __restrict__ adj, const float* __restrict__ e,
    const float* __restrict__ P2, const float* __restrict__ Q2,
    const short* __restrict__ W1cT, const short* __restrict__ W2T,
    const float* __restrict__ b2,
    const float* __restrict__ WJT, const float* __restrict__ WIT,
    const float* __restrict__ b3,
    float* __restrict__ Ai, float* __restrict__ Aj)
{
    __shared__ __align__(16) short s_h1[64][136];
    __shared__ __align__(16) float s_x[H0_];

    const int bi = blockIdx.x;
    conv_node(bi, adj, e, P2, Q2, W1cT, W2T, b2, s_h1, s_x);

    const int n = threadIdx.x;                 // 0..255
    float aI = b3[n], aJ = 0.f;
    const float* wj = WJT + n * H0_;
    const float* wi = WIT + n * H0_;
    #pragma unroll 4
    for (int k = 0; k < H0_; k += 4) {
        float4 x  = *(const float4*)(s_x + k);
        float4 vj = *(const float4*)(wj + k);
        float4 vi = *(const float4*)(wi + k);
        aJ = fmaf(x.x, vj.x, aJ);  aI = fmaf(x.x, vi.x, aI);
        aJ = fmaf(x.y, vj.y, aJ);  aI = fmaf(x.y, vi.y, aI);
        aJ = fmaf(x.z, vj.z, aJ);  aI = fmaf(x.z, vi.z, aI);
        aJ = fmaf(x.w, vj.w, aJ);  aI = fmaf(x.w, vi.w, aI);
    }
    Ai[bi * H2_ + n] = aI;
    Aj[bi * H2_ + n] = aJ;
}

// ---------------------------------------------------------------------------
// Pair output: block = 4 i's, wave = one i, lane=(jj,c): f = relu(Ai+Aj),
// z = f.Wo -> sigmoid. (verified in R3/R4)
// ---------------------------------------------------------------------------
__global__ __launch_bounds__(256) void pair_out_k(
    const float* __restrict__ Ai, const float* __restrict__ Aj,
    const float* __restrict__ Wo, const float* __restrict__ bo,
    float* __restrict__ out)
{
    const int blk  = blockIdx.x;
    const int b    = blk >> 6;
    const int i    = ((blk & 63) << 2) + (threadIdx.x >> 6);
    const int lane = threadIdx.x & 63;
    const int jj   = lane >> 4;
    const int c    = lane & 15;

    const float* ai = Ai + (b * V_ + i) * H2_ + c * 16;
    float4 a0 = *(const float4*)(ai);
    float4 a1 = *(const float4*)(ai + 4);
    float4 a2 = *(const float4*)(ai + 8);
    float4 a3 = *(const float4*)(ai + 12);
    const float* wo = Wo + c * 16;
    float4 w0 = *(const float4*)(wo);
    float4 w1 = *(const float4*)(wo + 4);
    float4 w2 = *(const float4*)(wo + 8);
    float4 w3 = *(const float4*)(wo + 12);
    const float bo0 = bo[0];

    for (int j0 = 0; j0 < V_; j0 += 4) {
        const int j = j0 + jj;
        const float* aj = Aj + (b * V_ + j) * H2_ + c * 16;
        float4 q0 = *(const float4*)(aj);
        float4 q1 = *(const float4*)(aj + 4);
        float4 q2 = *(const float4*)(aj + 8);
        float4 q3 = *(const float4*)(aj + 12);
        float p;
        p = fmaxf(a0.x + q0.x, 0.f) * w0.x;
        p = fmaf(fmaxf(a0.y + q0.y, 0.f), w0.y, p);
        p = fmaf(fmaxf(a0.z + q0.z, 0.f), w0.z, p);
        p = fmaf(fmaxf(a0.w + q0.w, 0.f), w0.w, p);
        p = fmaf(fmaxf(a1.x + q1.x, 0.f), w1.x, p);
        p = fmaf(fmaxf(a1.y + q1.y, 0.f), w1.y, p);
        p = fmaf(fmaxf(a1.z + q1.z, 0.f), w1.z, p);
        p = fmaf(fmaxf(a1.w + q1.w, 0.f), w1.w, p);
        p = fmaf(fmaxf(a2.x + q2.x, 0.f), w2.x, p);
        p = fmaf(fmaxf(a2.y + q2.y, 0.f), w2.y, p);
        p = fmaf(fmaxf(a2.z + q2.z, 0.f), w2.z, p);
        p = fmaf(fmaxf(a2.w + q2.w, 0.f), w2.w, p);
        p = fmaf(fmaxf(a3.x + q3.x, 0.f), w3.x, p);
        p = fmaf(fmaxf(a3.y + q3.y, 0.f), w3.y, p);
        p = fmaf(fmaxf(a3.z + q3.z, 0.f), w3.z, p);
        p = fmaf(fmaxf(a3.w + q3.w, 0.f), w3.w, p);
        #pragma unroll
        for (int off = 1; off < 16; off <<= 1)
            p += __shfl_xor(p, off, 64);
        if (c == 0)
            out[(b * V_ + i) * V_ + j] = 1.f / (1.f + __builtin_expf(-(p + bo0)));
    }
}

// ---------------------------------------------------------------------------
extern "C" void kernel_launch(void* const* d_in, const int* in_sizes, int n_in,
                              void* d_out, int out_size, void* d_ws, size_t ws_size,
                              hipStream_t stream) {
    const int*   adj   = (const int*)  d_in[0];
    const float* xf    = (const float*)d_in[1];
    const float* ea    = (const float*)d_in[2];
    const float* ec1W1 = (const float*)d_in[3];
    const float* ec1b1 = (const float*)d_in[4];
    const float* ec1W2 = (const float*)d_in[5];
    const float* ec1b2 = (const float*)d_in[6];
    const float* ec2W1 = (const float*)d_in[7];
    const float* ec2b1 = (const float*)d_in[8];
    const float* ec2W2 = (const float*)d_in[9];
    const float* ec2b2 = (const float*)d_in[10];
    const float* h3W   = (const float*)d_in[11];
    const float* h3b   = (const float*)d_in[12];
    const float* oW    = (const float*)d_in[13];
    const float* ob    = (const float*)d_in[14];
    float* out = (float*)d_out;

    const int NV = B_ * V_;                        // 1024 nodes
    float* P1  = (float*)d_ws;                     // NV*H0
    float* Q1  = P1  + NV * H0_;
    float* P2  = Q1  + NV * H0_;
    float* Q2  = P2  + NV * H0_;
    float* Ai  = Q2  + NV * H0_;                   // NV*H2
    float* Aj  = Ai  + NV * H2_;
    float* WPT = Aj  + NV * H2_;                   // 128*128
    float* WQT = WPT + H0_ * H0_;                  // 128*128
    float* WJT = WQT + H0_ * H0_;                  // 256*128
    float* WIT = WJT + H2_ * H0_;                  // 256*128
    short* wsW = (short*)(WIT + H2_ * H0_);        // 40960 bf16
    short* W1cT1 = wsW;
    short* W2T1  = wsW + 4096;
    short* W1cT2 = wsW + 20480;
    short* W2T2  = wsW + 24576;

    // K1: conv1 hoist (256 blocks) + all weight prep (544 blocks)
    pre1_k<<<800, 256, 0, stream>>>(xf, ec1W1, ec1b1, P1, Q1,
                                    ec1W1 + 2 * C1_ * H0_, ec1W2,
                                    ec2W1 + 2 * H0_ * H0_, ec2W2,
                                    ec2W1, h3W,
                                    wsW, WPT, WQT, WJT, WIT);
    // K2: conv1 (dense MFMA) + fused conv2 hoist
    conv1_k<<<NV, 256, 0, stream>>>(adj, ea, P1, Q1, W1cT1, W2T1, ec1b2,
                                    WPT, WQT, ec2b1, P2, Q2);
    // K3: conv2 (dense MFMA) + fused pair hoist
    conv2_k<<<NV, 256, 0, stream>>>(adj, ea, P2, Q2, W1cT2, W2T2, ec2b2,
                                    WJT, WIT, h3b, Ai, Aj);
    // K4: pair output
    pair_out_k<<<256, 256, 0, stream>>>(Ai, Aj, oW, ob, out);
}